// Round 1
// baseline (240928.955 us; speedup 1.0000x reference)
//
#include <hip/hip_runtime.h>
#include <math.h>

// WaveRNN autoregressive sampler, persistent-kernel fp32 baseline.
// 1024 sequential steps, 5 grid-barrier phases per step:
//   P1 : hp = W_hh_r @ hidden + b_hh_r  (2688x896 @ 896x32) + coarse GRU inline
//   P2 : h1c = relu(wc1 @ c_hid + bc1)
//   P34: logits_c = wc2 @ h1c + bc2 ; argmax -> nc ; fine GRU (needs nc)
//   P5 : h1f = relu(wf1 @ f_hid + bf1)
//   P67: logits_f = wf2 @ h1f + bf2 ; argmax -> nf
// Grid barrier = monotonic epoch flag array (1 release store/WG, read-only poll).

#define HALFN  448
#define SIZEN  896
#define RTOT   2688
#define NB     32
#define TSTEPS 1024
#define NWG    224
#define NTHR   256
#define CONDSTR (RTOT * TSTEPS)   // per-batch stride in conditional

// reordered row -> original row: chunks [cr,cu,ce,fr,fu,fe] <- orig chunks {0,2,4,1,3,5}
__device__ __forceinline__ int orig_row(int r) {
  int c = r / HALFN, o = r - c * HALFN;
  int oc = (c < 3) ? (2 * c) : (2 * (c - 3) + 1);
  return oc * HALFN + o;
}

__device__ __forceinline__ float sigm(float x) { return 1.0f / (1.0f + expf(-x)); }

struct SharedMem {
  float red[8][12][32];   // k-slice partial sums
  float hps[12][32];      // coarse hp staging (r rows 0-3, u rows 4-7, e rows 8-11)
  float h1col[HALFN];     // staged h1 column for FC2 phases
  float amaxv[4];
  int   amaxi[4];
  int   bcast;
};

__device__ __forceinline__ void gridbar(unsigned* flags, unsigned ep, int& dead) {
  __threadfence();
  __syncthreads();
  if (threadIdx.x == 0)
    __hip_atomic_store(&flags[blockIdx.x], ep, __ATOMIC_RELEASE, __HIP_MEMORY_SCOPE_AGENT);
  if (!dead) {
    int iters = 0;
    for (;;) {
      int ok = 1;
      if (threadIdx.x < NWG) {
        unsigned v = __hip_atomic_load(&flags[threadIdx.x], __ATOMIC_RELAXED, __HIP_MEMORY_SCOPE_AGENT);
        ok = (v >= ep) ? 1 : 0;
      }
      if (__syncthreads_and(ok)) break;
      if (++iters > (1 << 20)) { dead = 1; break; }  // anti-hang valve: fail visibly, not by timeout
      __builtin_amdgcn_s_sleep(2);
    }
  } else {
    __syncthreads();
  }
  __threadfence();
}

extern "C" __global__ void wavernn_init(float* ws) {
  int i = blockIdx.x * blockDim.x + threadIdx.x;
  int stride = gridDim.x * blockDim.x;
  for (int k = i; k < SIZEN * NB; k += stride) ws[k] = 0.0f;        // hidden buf0 = 0
  if (i < NB) {
    ws[114688 + i] = 128.0f;   // coarse sample init
    ws[114720 + i] = 0.0f;     // fine sample init
  }
  if (i < 256) ((unsigned*)(ws + 114752))[i] = 0u;                  // barrier flags
}

extern "C" __global__ void __launch_bounds__(NTHR)
wavernn_persist(const float* __restrict__ cond,
                const float* __restrict__ wci, const float* __restrict__ wfi,
                const float* __restrict__ whh, const float* __restrict__ bih,
                const float* __restrict__ bhh,
                const float* __restrict__ wc1, const float* __restrict__ bc1,
                const float* __restrict__ wc2, const float* __restrict__ bc2,
                const float* __restrict__ wf1, const float* __restrict__ bf1,
                const float* __restrict__ wf2, const float* __restrict__ bf2,
                float* __restrict__ out, float* ws) {
  __shared__ SharedMem sm;

  float* hidbuf0 = ws;                   // [896*32]
  float* hidbuf1 = ws + 28672;           // [896*32]
  float* hpf     = ws + 57344;           // [1344*32] fine hp
  float* h1g     = ws + 100352;          // [448*32]
  float* csamp   = ws + 114688;          // [32]
  float* fsamp   = ws + 114720;          // [32]
  unsigned* flags = (unsigned*)(ws + 114752);

  const int w = blockIdx.x, tid = threadIdx.x;
  const int b = tid & 31, ks = tid >> 5;       // dot-phase decomposition
  const bool isC = (w < 112);
  unsigned ep = 0;
  int dead = 0;

  // P1 row assignment (constant across steps): 12 rows per WG
  const float* wrp[12];
#pragma unroll
  for (int rr = 0; rr < 12; rr++) {
    int R = isC ? ((rr >> 2) * HALFN + w * 4 + (rr & 3))
                : (3 * HALFN + (w - 112) * 12 + rr);
    wrp[rr] = whh + (size_t)orig_row(R) * SIZEN;
  }

  for (int t = 0; t < TSTEPS; ++t) {
    const float* hc = (t & 1) ? hidbuf1 : hidbuf0;
    float*       hn = (t & 1) ? hidbuf0 : hidbuf1;

    // ---------------- P1: hp GEMM + coarse GRU ----------------
    {
      float acc[12];
#pragma unroll
      for (int rr = 0; rr < 12; rr++) acc[rr] = 0.0f;
      const int k0 = ks * 112;
      const float* hcol = hc + b;
#pragma unroll 2
      for (int k = k0; k < k0 + 112; k += 4) {
        float h0 = hcol[(k + 0) * 32], h1v = hcol[(k + 1) * 32];
        float h2 = hcol[(k + 2) * 32], h3  = hcol[(k + 3) * 32];
#pragma unroll
        for (int rr = 0; rr < 12; rr++) {
          const float4 wv = *(const float4*)(wrp[rr] + k);
          acc[rr] = fmaf(wv.x, h0, fmaf(wv.y, h1v, fmaf(wv.z, h2, fmaf(wv.w, h3, acc[rr]))));
        }
      }
#pragma unroll
      for (int rr = 0; rr < 12; rr++) sm.red[ks][rr][b] = acc[rr];
      __syncthreads();
      for (int idx = tid; idx < 384; idx += NTHR) {
        int rr = idx >> 5, bb = idx & 31;
        float s = 0.0f;
#pragma unroll
        for (int kk = 0; kk < 8; kk++) s += sm.red[kk][rr][bb];
        int R = isC ? ((rr >> 2) * HALFN + w * 4 + (rr & 3))
                    : (3 * HALFN + (w - 112) * 12 + rr);
        s += bhh[orig_row(R)];
        if (isC) sm.hps[rr][bb] = s;
        else     hpf[(size_t)(R - 3 * HALFN) * 32 + bb] = s;
      }
      __syncthreads();
      if (isC && tid < 128) {
        int ju = tid >> 5, bb = tid & 31;
        int j = w * 4 + ju;
        float scv = csamp[bb] * (2.0f / 255.0f) - 1.0f;
        float sfv = fsamp[bb] * (2.0f / 255.0f) - 1.0f;
        float ipr = wci[j * 2 + 0] * scv + wci[j * 2 + 1] * sfv
                  + cond[(size_t)bb * CONDSTR + (size_t)j * TSTEPS + t] + bih[j];
        float ipu = wci[(HALFN + j) * 2 + 0] * scv + wci[(HALFN + j) * 2 + 1] * sfv
                  + cond[(size_t)bb * CONDSTR + (size_t)(SIZEN + j) * TSTEPS + t] + bih[SIZEN + j];
        float ipe = wci[(SIZEN + j) * 2 + 0] * scv + wci[(SIZEN + j) * 2 + 1] * sfv
                  + cond[(size_t)bb * CONDSTR + (size_t)(1792 + j) * TSTEPS + t] + bih[1792 + j];
        float r = sigm(sm.hps[ju][bb] + ipr);
        float u = sigm(sm.hps[4 + ju][bb] + ipu);
        float e = tanhf(fmaf(r, sm.hps[8 + ju][bb], ipe));
        float oldh = hc[j * 32 + bb];
        hn[j * 32 + bb] = u * oldh + (1.0f - u) * e;
      }
    }
    gridbar(flags, ++ep, dead);

    // ---------------- P2: FC1 coarse ----------------
    {
      int r0 = w * 2;
      const int k0 = ks * 56;
      float a0 = 0.0f, a1 = 0.0f;
      const float* w0 = wc1 + (size_t)r0 * HALFN;
      const float* w1 = w0 + HALFN;
      const float* hcc = hn + b;   // c_hid rows 0..447
      for (int k = k0; k < k0 + 56; k += 4) {
        float h0 = hcc[(k + 0) * 32], h1v = hcc[(k + 1) * 32];
        float h2 = hcc[(k + 2) * 32], h3  = hcc[(k + 3) * 32];
        float4 v0 = *(const float4*)(w0 + k);
        a0 = fmaf(v0.x, h0, fmaf(v0.y, h1v, fmaf(v0.z, h2, fmaf(v0.w, h3, a0))));
        float4 v1 = *(const float4*)(w1 + k);
        a1 = fmaf(v1.x, h0, fmaf(v1.y, h1v, fmaf(v1.z, h2, fmaf(v1.w, h3, a1))));
      }
      sm.red[ks][0][b] = a0;
      sm.red[ks][1][b] = a1;
      __syncthreads();
      if (tid < 64) {
        int rr = tid >> 5, bb = tid & 31;
        float s = 0.0f;
#pragma unroll
        for (int kk = 0; kk < 8; kk++) s += sm.red[kk][rr][bb];
        s += bc1[r0 + rr];
        h1g[(size_t)(r0 + rr) * 32 + bb] = fmaxf(s, 0.0f);
      }
    }
    gridbar(flags, ++ep, dead);

    // ---------------- P34: FC2 coarse + argmax + fine GRU ----------------
    if (w < NB) {
      int b2 = w;
      for (int i = tid; i < HALFN; i += NTHR) sm.h1col[i] = h1g[(size_t)i * 32 + b2];
      __syncthreads();
      float accv = bc2[tid];
      const float* wrow2 = wc2 + (size_t)tid * HALFN;
      for (int i = 0; i < HALFN; i += 4) {
        float4 wv = *(const float4*)(wrow2 + i);
        accv = fmaf(wv.x, sm.h1col[i],
               fmaf(wv.y, sm.h1col[i + 1],
               fmaf(wv.z, sm.h1col[i + 2],
               fmaf(wv.w, sm.h1col[i + 3], accv))));
      }
      float v = accv; int vi = tid;
#pragma unroll
      for (int off = 1; off < 64; off <<= 1) {
        float ov = __shfl_xor(v, off);
        int   oi = __shfl_xor(vi, off);
        if (ov > v || (ov == v && oi < vi)) { v = ov; vi = oi; }
      }
      int wave = tid >> 6;
      if ((tid & 63) == 0) { sm.amaxv[wave] = v; sm.amaxi[wave] = vi; }
      __syncthreads();
      if (tid == 0) {
        float bv = sm.amaxv[0]; int bi = sm.amaxi[0];
#pragma unroll
        for (int q = 1; q < 4; q++) {
          float qv = sm.amaxv[q]; int qi = sm.amaxi[q];
          if (qv > bv || (qv == bv && qi < bi)) { bv = qv; bi = qi; }
        }
        sm.bcast = bi;
      }
      __syncthreads();
      int nc = sm.bcast;
      float snc = nc * (2.0f / 255.0f) - 1.0f;
      float scv = csamp[b2] * (2.0f / 255.0f) - 1.0f;
      float sfv = fsamp[b2] * (2.0f / 255.0f) - 1.0f;
      for (int j = tid; j < HALFN; j += NTHR) {
        float hpr = hpf[(size_t)j * 32 + b2];
        float hpu = hpf[(size_t)(HALFN + j) * 32 + b2];
        float hpe = hpf[(size_t)(SIZEN + j) * 32 + b2];
        float ipr = wfi[j * 3 + 0] * scv + wfi[j * 3 + 1] * sfv + wfi[j * 3 + 2] * snc
                  + cond[(size_t)b2 * CONDSTR + (size_t)(HALFN + j) * TSTEPS + t] + bih[HALFN + j];
        float ipu = wfi[(HALFN + j) * 3 + 0] * scv + wfi[(HALFN + j) * 3 + 1] * sfv + wfi[(HALFN + j) * 3 + 2] * snc
                  + cond[(size_t)b2 * CONDSTR + (size_t)(1344 + j) * TSTEPS + t] + bih[1344 + j];
        float ipe = wfi[(SIZEN + j) * 3 + 0] * scv + wfi[(SIZEN + j) * 3 + 1] * sfv + wfi[(SIZEN + j) * 3 + 2] * snc
                  + cond[(size_t)b2 * CONDSTR + (size_t)(2240 + j) * TSTEPS + t] + bih[2240 + j];
        float r = sigm(hpr + ipr);
        float u = sigm(hpu + ipu);
        float e = tanhf(fmaf(r, hpe, ipe));
        float oldh = hc[(size_t)(HALFN + j) * 32 + b2];
        hn[(size_t)(HALFN + j) * 32 + b2] = u * oldh + (1.0f - u) * e;
      }
      if (tid == 0) {
        out[(size_t)b2 * TSTEPS + t] = (float)nc;
        csamp[b2] = (float)nc;
      }
    }
    gridbar(flags, ++ep, dead);

    // ---------------- P5: FC1 fine ----------------
    {
      int r0 = w * 2;
      const int k0 = ks * 56;
      float a0 = 0.0f, a1 = 0.0f;
      const float* w0 = wf1 + (size_t)r0 * HALFN;
      const float* w1 = w0 + HALFN;
      const float* hff = hn + HALFN * 32 + b;   // f_hid rows 448..895
      for (int k = k0; k < k0 + 56; k += 4) {
        float h0 = hff[(k + 0) * 32], h1v = hff[(k + 1) * 32];
        float h2 = hff[(k + 2) * 32], h3  = hff[(k + 3) * 32];
        float4 v0 = *(const float4*)(w0 + k);
        a0 = fmaf(v0.x, h0, fmaf(v0.y, h1v, fmaf(v0.z, h2, fmaf(v0.w, h3, a0))));
        float4 v1 = *(const float4*)(w1 + k);
        a1 = fmaf(v1.x, h0, fmaf(v1.y, h1v, fmaf(v1.z, h2, fmaf(v1.w, h3, a1))));
      }
      sm.red[ks][0][b] = a0;
      sm.red[ks][1][b] = a1;
      __syncthreads();
      if (tid < 64) {
        int rr = tid >> 5, bb = tid & 31;
        float s = 0.0f;
#pragma unroll
        for (int kk = 0; kk < 8; kk++) s += sm.red[kk][rr][bb];
        s += bf1[r0 + rr];
        h1g[(size_t)(r0 + rr) * 32 + bb] = fmaxf(s, 0.0f);
      }
    }
    gridbar(flags, ++ep, dead);

    // ---------------- P67: FC2 fine + argmax ----------------
    if (w < NB) {
      int b2 = w;
      for (int i = tid; i < HALFN; i += NTHR) sm.h1col[i] = h1g[(size_t)i * 32 + b2];
      __syncthreads();
      float accv = bf2[tid];
      const float* wrow2 = wf2 + (size_t)tid * HALFN;
      for (int i = 0; i < HALFN; i += 4) {
        float4 wv = *(const float4*)(wrow2 + i);
        accv = fmaf(wv.x, sm.h1col[i],
               fmaf(wv.y, sm.h1col[i + 1],
               fmaf(wv.z, sm.h1col[i + 2],
               fmaf(wv.w, sm.h1col[i + 3], accv))));
      }
      float v = accv; int vi = tid;
#pragma unroll
      for (int off = 1; off < 64; off <<= 1) {
        float ov = __shfl_xor(v, off);
        int   oi = __shfl_xor(vi, off);
        if (ov > v || (ov == v && oi < vi)) { v = ov; vi = oi; }
      }
      int wave = tid >> 6;
      if ((tid & 63) == 0) { sm.amaxv[wave] = v; sm.amaxi[wave] = vi; }
      __syncthreads();
      if (tid == 0) {
        float bv = sm.amaxv[0]; int bi = sm.amaxi[0];
#pragma unroll
        for (int q = 1; q < 4; q++) {
          float qv = sm.amaxv[q]; int qi = sm.amaxi[q];
          if (qv > bv || (qv == bv && qi < bi)) { bv = qv; bi = qi; }
        }
        sm.bcast = bi;
      }
      __syncthreads();
      int nf = sm.bcast;
      if (tid == 0) {
        out[32768 + (size_t)b2 * TSTEPS + t] = (float)nf;
        fsamp[b2] = (float)nf;
      }
    }
    gridbar(flags, ++ep, dead);
  }

  // final hidden: [c_hid; f_hid] (896 x 32), newest buffer is buf0 after t=1023
  if (w < NB) {
    const float* hfin = hidbuf0;
    for (int j = tid; j < SIZEN; j += NTHR)
      out[65536 + (size_t)j * 32 + w] = hfin[(size_t)j * 32 + w];
  }
}

extern "C" void kernel_launch(void* const* d_in, const int* in_sizes, int n_in,
                              void* d_out, int out_size, void* d_ws, size_t ws_size,
                              hipStream_t stream) {
  const float* cond = (const float*)d_in[0];
  const float* wci  = (const float*)d_in[1];
  const float* wfi  = (const float*)d_in[2];
  const float* whh  = (const float*)d_in[3];
  const float* bih  = (const float*)d_in[4];
  const float* bhh  = (const float*)d_in[5];
  const float* wc1  = (const float*)d_in[6];
  const float* bc1  = (const float*)d_in[7];
  const float* wc2  = (const float*)d_in[8];
  const float* bc2  = (const float*)d_in[9];
  const float* wf1  = (const float*)d_in[10];
  const float* bf1  = (const float*)d_in[11];
  const float* wf2  = (const float*)d_in[12];
  const float* bf2  = (const float*)d_in[13];
  float* out = (float*)d_out;
  float* ws  = (float*)d_ws;

  hipLaunchKernelGGL(wavernn_init, dim3(64), dim3(NTHR), 0, stream, ws);
  hipLaunchKernelGGL(wavernn_persist, dim3(NWG), dim3(NTHR), 0, stream,
                     cond, wci, wfi, whh, bih, bhh,
                     wc1, bc1, wc2, bc2, wf1, bf1, wf2, bf2, out, ws);
}

// Round 2
// 82616.119 us; speedup vs baseline: 2.9162x; 2.9162x over previous
//
#include <hip/hip_runtime.h>
#include <math.h>

// WaveRNN autoregressive sampler, persistent kernel, fp32.
// Round 2: fence-free grid barriers. Cross-WG state goes through relaxed
// AGENT-scope atomics (coherent at the LLC, proven by round-1 flag behavior);
// weights/cond use plain cached loads and stay L2-resident because no fence
// ever invalidates L2. Round 1 spent ~97% of time re-fetching weights after
// every __threadfence() (FETCH_SIZE 9.4GB = weights x 1024 steps).

#define HALFN  448
#define SIZEN  896
#define RTOT   2688
#define NB     32
#define TSTEPS 1024
#define NWG    224
#define NTHR   256
#define CONDSTR (RTOT * TSTEPS)   // per-batch stride in conditional

// reordered row -> original row: chunks [cr,cu,ce,fr,fu,fe] <- orig chunks {0,2,4,1,3,5}
__device__ __forceinline__ int orig_row(int r) {
  int c = r / HALFN, o = r - c * HALFN;
  int oc = (c < 3) ? (2 * c) : (2 * (c - 3) + 1);
  return oc * HALFN + o;
}

__device__ __forceinline__ float sigm(float x) { return 1.0f / (1.0f + expf(-x)); }

// Cross-XCD coherent scalar access (bypasses L1/L2 to the coherent point).
__device__ __forceinline__ float gload(const float* p) {
  return __hip_atomic_load(const_cast<float*>(p), __ATOMIC_RELAXED, __HIP_MEMORY_SCOPE_AGENT);
}
__device__ __forceinline__ void gstore(float* p, float v) {
  __hip_atomic_store(p, v, __ATOMIC_RELAXED, __HIP_MEMORY_SCOPE_AGENT);
}

struct SharedMem {
  float red[8][12][32];   // k-slice partial sums
  float hps[12][32];      // coarse hp staging (r rows 0-3, u rows 4-7, e rows 8-11)
  float h1col[HALFN];     // staged h1 column for FC2 phases
  float amaxv[4];
  int   amaxi[4];
  int   bcast;
};

// Fence-free grid barrier:
//  - each wave drains its own vmem (all state stores are agent atomics that
//    land at the coherent point) before the workgroup barrier,
//  - one relaxed agent flag store per WG, relaxed polling.
// No cache maintenance anywhere -> L2 keeps the weights hot across steps.
__device__ __forceinline__ void gridbar(unsigned* flags, unsigned ep, int& dead) {
  asm volatile("s_waitcnt vmcnt(0)" ::: "memory");
  __syncthreads();
  if (threadIdx.x == 0)
    __hip_atomic_store(&flags[blockIdx.x], ep, __ATOMIC_RELAXED, __HIP_MEMORY_SCOPE_AGENT);
  if (!dead) {
    int iters = 0;
    for (;;) {
      int ok = 1;
      if (threadIdx.x < NWG) {
        unsigned v = __hip_atomic_load(&flags[threadIdx.x], __ATOMIC_RELAXED, __HIP_MEMORY_SCOPE_AGENT);
        ok = (v >= ep) ? 1 : 0;
      }
      if (__syncthreads_and(ok)) break;
      if (++iters > (1 << 20)) { dead = 1; break; }  // anti-hang valve
      __builtin_amdgcn_s_sleep(2);
    }
  } else {
    __syncthreads();
  }
}

extern "C" __global__ void wavernn_init(float* ws) {
  int i = blockIdx.x * blockDim.x + threadIdx.x;
  int stride = gridDim.x * blockDim.x;
  for (int k = i; k < SIZEN * NB; k += stride) ws[k] = 0.0f;        // hidden buf0 = 0
  if (i < NB) {
    ws[114688 + i] = 128.0f;   // coarse sample init
    ws[114720 + i] = 0.0f;     // fine sample init
  }
  if (i < 256) ((unsigned*)(ws + 114752))[i] = 0u;                  // barrier flags
}

extern "C" __global__ void __launch_bounds__(NTHR)
wavernn_persist(const float* __restrict__ cond,
                const float* __restrict__ wci, const float* __restrict__ wfi,
                const float* __restrict__ whh, const float* __restrict__ bih,
                const float* __restrict__ bhh,
                const float* __restrict__ wc1, const float* __restrict__ bc1,
                const float* __restrict__ wc2, const float* __restrict__ bc2,
                const float* __restrict__ wf1, const float* __restrict__ bf1,
                const float* __restrict__ wf2, const float* __restrict__ bf2,
                float* __restrict__ out, float* ws) {
  __shared__ SharedMem sm;

  float* hidbuf0 = ws;                   // [896*32]
  float* hidbuf1 = ws + 28672;           // [896*32]
  float* hpf     = ws + 57344;           // [1344*32] fine hp
  float* h1g     = ws + 100352;          // [448*32]
  float* csamp   = ws + 114688;          // [32]
  float* fsamp   = ws + 114720;          // [32]
  unsigned* flags = (unsigned*)(ws + 114752);

  const int w = blockIdx.x, tid = threadIdx.x;
  const int b = tid & 31, ks = tid >> 5;       // dot-phase decomposition
  const bool isC = (w < 112);
  unsigned ep = 0;
  int dead = 0;

  // P1 row assignment (constant across steps): 12 rows per WG
  const float* wrp[12];
#pragma unroll
  for (int rr = 0; rr < 12; rr++) {
    int R = isC ? ((rr >> 2) * HALFN + w * 4 + (rr & 3))
                : (3 * HALFN + (w - 112) * 12 + rr);
    wrp[rr] = whh + (size_t)orig_row(R) * SIZEN;
  }

  for (int t = 0; t < TSTEPS; ++t) {
    const float* hc = (t & 1) ? hidbuf1 : hidbuf0;
    float*       hn = (t & 1) ? hidbuf0 : hidbuf1;

    // ---------------- P1: hp GEMM + coarse GRU ----------------
    {
      float acc[12];
#pragma unroll
      for (int rr = 0; rr < 12; rr++) acc[rr] = 0.0f;
      const int k0 = ks * 112;
      const float* hcol = hc + b;
#pragma unroll 2
      for (int k = k0; k < k0 + 112; k += 4) {
        float h0 = gload(&hcol[(k + 0) * 32]), h1v = gload(&hcol[(k + 1) * 32]);
        float h2 = gload(&hcol[(k + 2) * 32]), h3  = gload(&hcol[(k + 3) * 32]);
#pragma unroll
        for (int rr = 0; rr < 12; rr++) {
          const float4 wv = *(const float4*)(wrp[rr] + k);
          acc[rr] = fmaf(wv.x, h0, fmaf(wv.y, h1v, fmaf(wv.z, h2, fmaf(wv.w, h3, acc[rr]))));
        }
      }
#pragma unroll
      for (int rr = 0; rr < 12; rr++) sm.red[ks][rr][b] = acc[rr];
      __syncthreads();
      for (int idx = tid; idx < 384; idx += NTHR) {
        int rr = idx >> 5, bb = idx & 31;
        float s = 0.0f;
#pragma unroll
        for (int kk = 0; kk < 8; kk++) s += sm.red[kk][rr][bb];
        int R = isC ? ((rr >> 2) * HALFN + w * 4 + (rr & 3))
                    : (3 * HALFN + (w - 112) * 12 + rr);
        s += bhh[orig_row(R)];
        if (isC) sm.hps[rr][bb] = s;
        else     gstore(&hpf[(size_t)(R - 3 * HALFN) * 32 + bb], s);
      }
      __syncthreads();
      if (isC && tid < 128) {
        int ju = tid >> 5, bb = tid & 31;
        int j = w * 4 + ju;
        float scv = gload(&csamp[bb]) * (2.0f / 255.0f) - 1.0f;
        float sfv = gload(&fsamp[bb]) * (2.0f / 255.0f) - 1.0f;
        float ipr = wci[j * 2 + 0] * scv + wci[j * 2 + 1] * sfv
                  + cond[(size_t)bb * CONDSTR + (size_t)j * TSTEPS + t] + bih[j];
        float ipu = wci[(HALFN + j) * 2 + 0] * scv + wci[(HALFN + j) * 2 + 1] * sfv
                  + cond[(size_t)bb * CONDSTR + (size_t)(SIZEN + j) * TSTEPS + t] + bih[SIZEN + j];
        float ipe = wci[(SIZEN + j) * 2 + 0] * scv + wci[(SIZEN + j) * 2 + 1] * sfv
                  + cond[(size_t)bb * CONDSTR + (size_t)(1792 + j) * TSTEPS + t] + bih[1792 + j];
        float r = sigm(sm.hps[ju][bb] + ipr);
        float u = sigm(sm.hps[4 + ju][bb] + ipu);
        float e = tanhf(fmaf(r, sm.hps[8 + ju][bb], ipe));
        float oldh = gload(&hc[j * 32 + bb]);
        gstore(&hn[j * 32 + bb], u * oldh + (1.0f - u) * e);
      }
    }
    gridbar(flags, ++ep, dead);

    // ---------------- P2: FC1 coarse ----------------
    {
      int r0 = w * 2;
      const int k0 = ks * 56;
      float a0 = 0.0f, a1 = 0.0f;
      const float* w0 = wc1 + (size_t)r0 * HALFN;
      const float* w1 = w0 + HALFN;
      const float* hcc = hn + b;   // c_hid rows 0..447
      for (int k = k0; k < k0 + 56; k += 4) {
        float h0 = gload(&hcc[(k + 0) * 32]), h1v = gload(&hcc[(k + 1) * 32]);
        float h2 = gload(&hcc[(k + 2) * 32]), h3  = gload(&hcc[(k + 3) * 32]);
        float4 v0 = *(const float4*)(w0 + k);
        a0 = fmaf(v0.x, h0, fmaf(v0.y, h1v, fmaf(v0.z, h2, fmaf(v0.w, h3, a0))));
        float4 v1 = *(const float4*)(w1 + k);
        a1 = fmaf(v1.x, h0, fmaf(v1.y, h1v, fmaf(v1.z, h2, fmaf(v1.w, h3, a1))));
      }
      sm.red[ks][0][b] = a0;
      sm.red[ks][1][b] = a1;
      __syncthreads();
      if (tid < 64) {
        int rr = tid >> 5, bb = tid & 31;
        float s = 0.0f;
#pragma unroll
        for (int kk = 0; kk < 8; kk++) s += sm.red[kk][rr][bb];
        s += bc1[r0 + rr];
        gstore(&h1g[(size_t)(r0 + rr) * 32 + bb], fmaxf(s, 0.0f));
      }
    }
    gridbar(flags, ++ep, dead);

    // ---------------- P34: FC2 coarse + argmax + fine GRU ----------------
    if (w < NB) {
      int b2 = w;
      for (int i = tid; i < HALFN; i += NTHR) sm.h1col[i] = gload(&h1g[(size_t)i * 32 + b2]);
      __syncthreads();
      float accv = bc2[tid];
      const float* wrow2 = wc2 + (size_t)tid * HALFN;
      for (int i = 0; i < HALFN; i += 4) {
        float4 wv = *(const float4*)(wrow2 + i);
        accv = fmaf(wv.x, sm.h1col[i],
               fmaf(wv.y, sm.h1col[i + 1],
               fmaf(wv.z, sm.h1col[i + 2],
               fmaf(wv.w, sm.h1col[i + 3], accv))));
      }
      float v = accv; int vi = tid;
#pragma unroll
      for (int off = 1; off < 64; off <<= 1) {
        float ov = __shfl_xor(v, off);
        int   oi = __shfl_xor(vi, off);
        if (ov > v || (ov == v && oi < vi)) { v = ov; vi = oi; }
      }
      int wave = tid >> 6;
      if ((tid & 63) == 0) { sm.amaxv[wave] = v; sm.amaxi[wave] = vi; }
      __syncthreads();
      if (tid == 0) {
        float bv = sm.amaxv[0]; int bi = sm.amaxi[0];
#pragma unroll
        for (int q = 1; q < 4; q++) {
          float qv = sm.amaxv[q]; int qi = sm.amaxi[q];
          if (qv > bv || (qv == bv && qi < bi)) { bv = qv; bi = qi; }
        }
        sm.bcast = bi;
      }
      __syncthreads();
      int nc = sm.bcast;
      float snc = nc * (2.0f / 255.0f) - 1.0f;
      float scv = gload(&csamp[b2]) * (2.0f / 255.0f) - 1.0f;
      float sfv = gload(&fsamp[b2]) * (2.0f / 255.0f) - 1.0f;
      for (int j = tid; j < HALFN; j += NTHR) {
        float hpr = gload(&hpf[(size_t)j * 32 + b2]);
        float hpu = gload(&hpf[(size_t)(HALFN + j) * 32 + b2]);
        float hpe = gload(&hpf[(size_t)(SIZEN + j) * 32 + b2]);
        float ipr = wfi[j * 3 + 0] * scv + wfi[j * 3 + 1] * sfv + wfi[j * 3 + 2] * snc
                  + cond[(size_t)b2 * CONDSTR + (size_t)(HALFN + j) * TSTEPS + t] + bih[HALFN + j];
        float ipu = wfi[(HALFN + j) * 3 + 0] * scv + wfi[(HALFN + j) * 3 + 1] * sfv + wfi[(HALFN + j) * 3 + 2] * snc
                  + cond[(size_t)b2 * CONDSTR + (size_t)(1344 + j) * TSTEPS + t] + bih[1344 + j];
        float ipe = wfi[(SIZEN + j) * 3 + 0] * scv + wfi[(SIZEN + j) * 3 + 1] * sfv + wfi[(SIZEN + j) * 3 + 2] * snc
                  + cond[(size_t)b2 * CONDSTR + (size_t)(2240 + j) * TSTEPS + t] + bih[2240 + j];
        float r = sigm(hpr + ipr);
        float u = sigm(hpu + ipu);
        float e = tanhf(fmaf(r, hpe, ipe));
        float oldh = gload(&hc[(size_t)(HALFN + j) * 32 + b2]);
        gstore(&hn[(size_t)(HALFN + j) * 32 + b2], u * oldh + (1.0f - u) * e);
      }
      if (tid == 0) {
        out[(size_t)b2 * TSTEPS + t] = (float)nc;
        gstore(&csamp[b2], (float)nc);
      }
    }
    gridbar(flags, ++ep, dead);

    // ---------------- P5: FC1 fine ----------------
    {
      int r0 = w * 2;
      const int k0 = ks * 56;
      float a0 = 0.0f, a1 = 0.0f;
      const float* w0 = wf1 + (size_t)r0 * HALFN;
      const float* w1 = w0 + HALFN;
      const float* hff = hn + HALFN * 32 + b;   // f_hid rows 448..895
      for (int k = k0; k < k0 + 56; k += 4) {
        float h0 = gload(&hff[(k + 0) * 32]), h1v = gload(&hff[(k + 1) * 32]);
        float h2 = gload(&hff[(k + 2) * 32]), h3  = gload(&hff[(k + 3) * 32]);
        float4 v0 = *(const float4*)(w0 + k);
        a0 = fmaf(v0.x, h0, fmaf(v0.y, h1v, fmaf(v0.z, h2, fmaf(v0.w, h3, a0))));
        float4 v1 = *(const float4*)(w1 + k);
        a1 = fmaf(v1.x, h0, fmaf(v1.y, h1v, fmaf(v1.z, h2, fmaf(v1.w, h3, a1))));
      }
      sm.red[ks][0][b] = a0;
      sm.red[ks][1][b] = a1;
      __syncthreads();
      if (tid < 64) {
        int rr = tid >> 5, bb = tid & 31;
        float s = 0.0f;
#pragma unroll
        for (int kk = 0; kk < 8; kk++) s += sm.red[kk][rr][bb];
        s += bf1[r0 + rr];
        gstore(&h1g[(size_t)(r0 + rr) * 32 + bb], fmaxf(s, 0.0f));
      }
    }
    gridbar(flags, ++ep, dead);

    // ---------------- P67: FC2 fine + argmax ----------------
    if (w < NB) {
      int b2 = w;
      for (int i = tid; i < HALFN; i += NTHR) sm.h1col[i] = gload(&h1g[(size_t)i * 32 + b2]);
      __syncthreads();
      float accv = bf2[tid];
      const float* wrow2 = wf2 + (size_t)tid * HALFN;
      for (int i = 0; i < HALFN; i += 4) {
        float4 wv = *(const float4*)(wrow2 + i);
        accv = fmaf(wv.x, sm.h1col[i],
               fmaf(wv.y, sm.h1col[i + 1],
               fmaf(wv.z, sm.h1col[i + 2],
               fmaf(wv.w, sm.h1col[i + 3], accv))));
      }
      float v = accv; int vi = tid;
#pragma unroll
      for (int off = 1; off < 64; off <<= 1) {
        float ov = __shfl_xor(v, off);
        int   oi = __shfl_xor(vi, off);
        if (ov > v || (ov == v && oi < vi)) { v = ov; vi = oi; }
      }
      int wave = tid >> 6;
      if ((tid & 63) == 0) { sm.amaxv[wave] = v; sm.amaxi[wave] = vi; }
      __syncthreads();
      if (tid == 0) {
        float bv = sm.amaxv[0]; int bi = sm.amaxi[0];
#pragma unroll
        for (int q = 1; q < 4; q++) {
          float qv = sm.amaxv[q]; int qi = sm.amaxi[q];
          if (qv > bv || (qv == bv && qi < bi)) { bv = qv; bi = qi; }
        }
        sm.bcast = bi;
      }
      __syncthreads();
      int nf = sm.bcast;
      if (tid == 0) {
        out[32768 + (size_t)b2 * TSTEPS + t] = (float)nf;
        gstore(&fsamp[b2], (float)nf);
      }
    }
    gridbar(flags, ++ep, dead);
  }

  // final hidden: [c_hid; f_hid] (896 x 32), newest buffer is buf0 after t=1023
  if (w < NB) {
    for (int j = tid; j < SIZEN; j += NTHR)
      out[65536 + (size_t)j * 32 + w] = gload(&hidbuf0[(size_t)j * 32 + w]);
  }
}

extern "C" void kernel_launch(void* const* d_in, const int* in_sizes, int n_in,
                              void* d_out, int out_size, void* d_ws, size_t ws_size,
                              hipStream_t stream) {
  const float* cond = (const float*)d_in[0];
  const float* wci  = (const float*)d_in[1];
  const float* wfi  = (const float*)d_in[2];
  const float* whh  = (const float*)d_in[3];
  const float* bih  = (const float*)d_in[4];
  const float* bhh  = (const float*)d_in[5];
  const float* wc1  = (const float*)d_in[6];
  const float* bc1  = (const float*)d_in[7];
  const float* wc2  = (const float*)d_in[8];
  const float* bc2  = (const float*)d_in[9];
  const float* wf1  = (const float*)d_in[10];
  const float* bf1  = (const float*)d_in[11];
  const float* wf2  = (const float*)d_in[12];
  const float* bf2  = (const float*)d_in[13];
  float* out = (float*)d_out;
  float* ws  = (float*)d_ws;

  hipLaunchKernelGGL(wavernn_init, dim3(64), dim3(NTHR), 0, stream, ws);
  hipLaunchKernelGGL(wavernn_persist, dim3(NWG), dim3(NTHR), 0, stream,
                     cond, wci, wfi, whh, bih, bhh,
                     wc1, bc1, wc2, bc2, wf1, bf1, wf2, bf2, out, ws);
}

// Round 3
// 71834.625 us; speedup vs baseline: 3.3539x; 1.1501x over previous
//
#include <hip/hip_runtime.h>
#include <math.h>

// WaveRNN autoregressive sampler, persistent kernel, fp32.
// Round 3: per-WG weights (whh 12 rows, wc1/wf1 2 rows each) staged in LDS
// once before the t-loop. Round 2 showed whh missing L2 every step
// (FETCH = 10.1 MB/step = whh + cond exactly): per-XCD working set ~3.5 MB
// vs 4 MB L2 -> thrash. LDS removes 11.2 MB/step of L2 demand entirely.
// Grid barrier stays fence-free (relaxed AGENT atomics, proven round 2).

#define HALFN  448
#define SIZEN  896
#define RTOT   2688
#define NB     32
#define TSTEPS 1024
#define NWG    224
#define NTHR   256
#define CONDSTR (RTOT * TSTEPS)   // per-batch stride in conditional

// reordered row -> original row: chunks [cr,cu,ce,fr,fu,fe] <- orig chunks {0,2,4,1,3,5}
__device__ __forceinline__ int orig_row(int r) {
  int c = r / HALFN, o = r - c * HALFN;
  int oc = (c < 3) ? (2 * c) : (2 * (c - 3) + 1);
  return oc * HALFN + o;
}

__device__ __forceinline__ float sigm(float x) { return 1.0f / (1.0f + expf(-x)); }

// Cross-XCD coherent scalar access (coherent at the LLC; round-2 verified).
__device__ __forceinline__ float gload(const float* p) {
  return __hip_atomic_load(const_cast<float*>(p), __ATOMIC_RELAXED, __HIP_MEMORY_SCOPE_AGENT);
}
__device__ __forceinline__ void gstore(float* p, float v) {
  __hip_atomic_store(p, v, __ATOMIC_RELAXED, __HIP_MEMORY_SCOPE_AGENT);
}

struct __align__(16) SharedMem {
  float whh_lds[12][SIZEN];   // 43008 B  per-WG rows of w_hh (reordered order)
  float wcf1[4][HALFN];       //  7168 B  wc1 rows r0,r0+1 ; wf1 rows r0,r0+1
  float red[8][12][32];       // 12288 B  k-slice partial sums
  float hps[12][32];          //  1536 B  coarse hp staging
  float h1col[HALFN];         //  1792 B  staged h1 column for FC2 phases
  float amaxv[4];
  int   amaxi[4];
  int   bcast;
};

// Fence-free grid barrier: drain own vmem, one relaxed agent flag store per
// WG, relaxed polling. No cache maintenance -> L2/LDS stay hot.
__device__ __forceinline__ void gridbar(unsigned* flags, unsigned ep, int& dead) {
  asm volatile("s_waitcnt vmcnt(0)" ::: "memory");
  __syncthreads();
  if (threadIdx.x == 0)
    __hip_atomic_store(&flags[blockIdx.x], ep, __ATOMIC_RELAXED, __HIP_MEMORY_SCOPE_AGENT);
  if (!dead) {
    int iters = 0;
    for (;;) {
      int ok = 1;
      if (threadIdx.x < NWG) {
        unsigned v = __hip_atomic_load(&flags[threadIdx.x], __ATOMIC_RELAXED, __HIP_MEMORY_SCOPE_AGENT);
        ok = (v >= ep) ? 1 : 0;
      }
      if (__syncthreads_and(ok)) break;
      if (++iters > (1 << 20)) { dead = 1; break; }  // anti-hang valve
      __builtin_amdgcn_s_sleep(2);
    }
  } else {
    __syncthreads();
  }
}

extern "C" __global__ void wavernn_init(float* ws) {
  int i = blockIdx.x * blockDim.x + threadIdx.x;
  int stride = gridDim.x * blockDim.x;
  for (int k = i; k < SIZEN * NB; k += stride) ws[k] = 0.0f;        // hidden buf0 = 0
  if (i < NB) {
    ws[114688 + i] = 128.0f;   // coarse sample init
    ws[114720 + i] = 0.0f;     // fine sample init
  }
  if (i < 256) ((unsigned*)(ws + 114752))[i] = 0u;                  // barrier flags
}

extern "C" __global__ void __launch_bounds__(NTHR)
wavernn_persist(const float* __restrict__ cond,
                const float* __restrict__ wci, const float* __restrict__ wfi,
                const float* __restrict__ whh, const float* __restrict__ bih,
                const float* __restrict__ bhh,
                const float* __restrict__ wc1, const float* __restrict__ bc1,
                const float* __restrict__ wc2, const float* __restrict__ bc2,
                const float* __restrict__ wf1, const float* __restrict__ bf1,
                const float* __restrict__ wf2, const float* __restrict__ bf2,
                float* __restrict__ out, float* ws) {
  __shared__ SharedMem sm;

  float* hidbuf0 = ws;                   // [896*32]
  float* hidbuf1 = ws + 28672;           // [896*32]
  float* hpf     = ws + 57344;           // [1344*32] fine hp
  float* h1g     = ws + 100352;          // [448*32]
  float* csamp   = ws + 114688;          // [32]
  float* fsamp   = ws + 114720;          // [32]
  unsigned* flags = (unsigned*)(ws + 114752);

  const int w = blockIdx.x, tid = threadIdx.x;
  const int b = tid & 31, ks = tid >> 5;       // dot-phase decomposition
  const bool isC = (w < 112);
  unsigned ep = 0;
  int dead = 0;

  // ---- one-time staging of per-WG weights into LDS ----
  {
#pragma unroll
    for (int rr = 0; rr < 12; rr++) {
      int R = isC ? ((rr >> 2) * HALFN + w * 4 + (rr & 3))
                  : (3 * HALFN + (w - 112) * 12 + rr);
      const float* src = whh + (size_t)orig_row(R) * SIZEN;
      for (int k = tid * 4; k < SIZEN; k += NTHR * 4)
        *(float4*)&sm.whh_lds[rr][k] = *(const float4*)&src[k];
    }
    int r0 = w * 2;
    for (int k = tid * 4; k < HALFN; k += NTHR * 4) {
      *(float4*)&sm.wcf1[0][k] = *(const float4*)&wc1[(size_t)r0 * HALFN + k];
      *(float4*)&sm.wcf1[1][k] = *(const float4*)&wc1[(size_t)(r0 + 1) * HALFN + k];
      *(float4*)&sm.wcf1[2][k] = *(const float4*)&wf1[(size_t)r0 * HALFN + k];
      *(float4*)&sm.wcf1[3][k] = *(const float4*)&wf1[(size_t)(r0 + 1) * HALFN + k];
    }
    __syncthreads();
  }

  for (int t = 0; t < TSTEPS; ++t) {
    const float* hc = (t & 1) ? hidbuf1 : hidbuf0;
    float*       hn = (t & 1) ? hidbuf0 : hidbuf1;

    // ---------------- P1: hp GEMM (LDS weights) + coarse GRU ----------------
    {
      float acc[12];
#pragma unroll
      for (int rr = 0; rr < 12; rr++) acc[rr] = 0.0f;
      const int k0 = ks * 112;
      const float* hcol = hc + b;
#pragma unroll 4
      for (int k = k0; k < k0 + 112; k += 4) {
        float h0 = gload(&hcol[(k + 0) * 32]), h1v = gload(&hcol[(k + 1) * 32]);
        float h2 = gload(&hcol[(k + 2) * 32]), h3  = gload(&hcol[(k + 3) * 32]);
#pragma unroll
        for (int rr = 0; rr < 12; rr++) {
          const float4 wv = *(const float4*)&sm.whh_lds[rr][k];
          acc[rr] = fmaf(wv.x, h0, fmaf(wv.y, h1v, fmaf(wv.z, h2, fmaf(wv.w, h3, acc[rr]))));
        }
      }
      __syncthreads();   // protect sm.red reuse ordering across phases
#pragma unroll
      for (int rr = 0; rr < 12; rr++) sm.red[ks][rr][b] = acc[rr];
      __syncthreads();
      for (int idx = tid; idx < 384; idx += NTHR) {
        int rr = idx >> 5, bb = idx & 31;
        float s = 0.0f;
#pragma unroll
        for (int kk = 0; kk < 8; kk++) s += sm.red[kk][rr][bb];
        int R = isC ? ((rr >> 2) * HALFN + w * 4 + (rr & 3))
                    : (3 * HALFN + (w - 112) * 12 + rr);
        s += bhh[orig_row(R)];
        if (isC) sm.hps[rr][bb] = s;
        else     gstore(&hpf[(size_t)(R - 3 * HALFN) * 32 + bb], s);
      }
      __syncthreads();
      if (isC && tid < 128) {
        int ju = tid >> 5, bb = tid & 31;
        int j = w * 4 + ju;
        float scv = gload(&csamp[bb]) * (2.0f / 255.0f) - 1.0f;
        float sfv = gload(&fsamp[bb]) * (2.0f / 255.0f) - 1.0f;
        float ipr = wci[j * 2 + 0] * scv + wci[j * 2 + 1] * sfv
                  + cond[(size_t)bb * CONDSTR + (size_t)j * TSTEPS + t] + bih[j];
        float ipu = wci[(HALFN + j) * 2 + 0] * scv + wci[(HALFN + j) * 2 + 1] * sfv
                  + cond[(size_t)bb * CONDSTR + (size_t)(SIZEN + j) * TSTEPS + t] + bih[SIZEN + j];
        float ipe = wci[(SIZEN + j) * 2 + 0] * scv + wci[(SIZEN + j) * 2 + 1] * sfv
                  + cond[(size_t)bb * CONDSTR + (size_t)(1792 + j) * TSTEPS + t] + bih[1792 + j];
        float r = sigm(sm.hps[ju][bb] + ipr);
        float u = sigm(sm.hps[4 + ju][bb] + ipu);
        float e = tanhf(fmaf(r, sm.hps[8 + ju][bb], ipe));
        float oldh = gload(&hc[j * 32 + bb]);
        gstore(&hn[j * 32 + bb], u * oldh + (1.0f - u) * e);
      }
    }
    gridbar(flags, ++ep, dead);

    // ---------------- P2: FC1 coarse (LDS weights) ----------------
    {
      int r0 = w * 2;
      const int k0 = ks * 56;
      float a0 = 0.0f, a1 = 0.0f;
      const float* hcc = hn + b;   // c_hid rows 0..447
#pragma unroll 2
      for (int k = k0; k < k0 + 56; k += 4) {
        float h0 = gload(&hcc[(k + 0) * 32]), h1v = gload(&hcc[(k + 1) * 32]);
        float h2 = gload(&hcc[(k + 2) * 32]), h3  = gload(&hcc[(k + 3) * 32]);
        float4 v0 = *(const float4*)&sm.wcf1[0][k];
        a0 = fmaf(v0.x, h0, fmaf(v0.y, h1v, fmaf(v0.z, h2, fmaf(v0.w, h3, a0))));
        float4 v1 = *(const float4*)&sm.wcf1[1][k];
        a1 = fmaf(v1.x, h0, fmaf(v1.y, h1v, fmaf(v1.z, h2, fmaf(v1.w, h3, a1))));
      }
      sm.red[ks][0][b] = a0;
      sm.red[ks][1][b] = a1;
      __syncthreads();
      if (tid < 64) {
        int rr = tid >> 5, bb = tid & 31;
        float s = 0.0f;
#pragma unroll
        for (int kk = 0; kk < 8; kk++) s += sm.red[kk][rr][bb];
        s += bc1[r0 + rr];
        gstore(&h1g[(size_t)(r0 + rr) * 32 + bb], fmaxf(s, 0.0f));
      }
    }
    gridbar(flags, ++ep, dead);

    // ---------------- P34: FC2 coarse + argmax + fine GRU ----------------
    if (w < NB) {
      int b2 = w;
      for (int i = tid; i < HALFN; i += NTHR) sm.h1col[i] = gload(&h1g[(size_t)i * 32 + b2]);
      __syncthreads();
      float accv = bc2[tid];
      const float* wrow2 = wc2 + (size_t)tid * HALFN;
      for (int i = 0; i < HALFN; i += 4) {
        float4 wv = *(const float4*)(wrow2 + i);
        accv = fmaf(wv.x, sm.h1col[i],
               fmaf(wv.y, sm.h1col[i + 1],
               fmaf(wv.z, sm.h1col[i + 2],
               fmaf(wv.w, sm.h1col[i + 3], accv))));
      }
      float v = accv; int vi = tid;
#pragma unroll
      for (int off = 1; off < 64; off <<= 1) {
        float ov = __shfl_xor(v, off);
        int   oi = __shfl_xor(vi, off);
        if (ov > v || (ov == v && oi < vi)) { v = ov; vi = oi; }
      }
      int wave = tid >> 6;
      if ((tid & 63) == 0) { sm.amaxv[wave] = v; sm.amaxi[wave] = vi; }
      __syncthreads();
      if (tid == 0) {
        float bv = sm.amaxv[0]; int bi = sm.amaxi[0];
#pragma unroll
        for (int q = 1; q < 4; q++) {
          float qv = sm.amaxv[q]; int qi = sm.amaxi[q];
          if (qv > bv || (qv == bv && qi < bi)) { bv = qv; bi = qi; }
        }
        sm.bcast = bi;
      }
      __syncthreads();
      int nc = sm.bcast;
      float snc = nc * (2.0f / 255.0f) - 1.0f;
      float scv = gload(&csamp[b2]) * (2.0f / 255.0f) - 1.0f;
      float sfv = gload(&fsamp[b2]) * (2.0f / 255.0f) - 1.0f;
      for (int j = tid; j < HALFN; j += NTHR) {
        float hpr = gload(&hpf[(size_t)j * 32 + b2]);
        float hpu = gload(&hpf[(size_t)(HALFN + j) * 32 + b2]);
        float hpe = gload(&hpf[(size_t)(SIZEN + j) * 32 + b2]);
        float ipr = wfi[j * 3 + 0] * scv + wfi[j * 3 + 1] * sfv + wfi[j * 3 + 2] * snc
                  + cond[(size_t)b2 * CONDSTR + (size_t)(HALFN + j) * TSTEPS + t] + bih[HALFN + j];
        float ipu = wfi[(HALFN + j) * 3 + 0] * scv + wfi[(HALFN + j) * 3 + 1] * sfv + wfi[(HALFN + j) * 3 + 2] * snc
                  + cond[(size_t)b2 * CONDSTR + (size_t)(1344 + j) * TSTEPS + t] + bih[1344 + j];
        float ipe = wfi[(SIZEN + j) * 3 + 0] * scv + wfi[(SIZEN + j) * 3 + 1] * sfv + wfi[(SIZEN + j) * 3 + 2] * snc
                  + cond[(size_t)b2 * CONDSTR + (size_t)(2240 + j) * TSTEPS + t] + bih[2240 + j];
        float r = sigm(hpr + ipr);
        float u = sigm(hpu + ipu);
        float e = tanhf(fmaf(r, hpe, ipe));
        float oldh = gload(&hc[(size_t)(HALFN + j) * 32 + b2]);
        gstore(&hn[(size_t)(HALFN + j) * 32 + b2], u * oldh + (1.0f - u) * e);
      }
      if (tid == 0) {
        out[(size_t)b2 * TSTEPS + t] = (float)nc;
        gstore(&csamp[b2], (float)nc);
      }
    }
    gridbar(flags, ++ep, dead);

    // ---------------- P5: FC1 fine (LDS weights) ----------------
    {
      int r0 = w * 2;
      const int k0 = ks * 56;
      float a0 = 0.0f, a1 = 0.0f;
      const float* hff = hn + HALFN * 32 + b;   // f_hid rows 448..895
#pragma unroll 2
      for (int k = k0; k < k0 + 56; k += 4) {
        float h0 = gload(&hff[(k + 0) * 32]), h1v = gload(&hff[(k + 1) * 32]);
        float h2 = gload(&hff[(k + 2) * 32]), h3  = gload(&hff[(k + 3) * 32]);
        float4 v0 = *(const float4*)&sm.wcf1[2][k];
        a0 = fmaf(v0.x, h0, fmaf(v0.y, h1v, fmaf(v0.z, h2, fmaf(v0.w, h3, a0))));
        float4 v1 = *(const float4*)&sm.wcf1[3][k];
        a1 = fmaf(v1.x, h0, fmaf(v1.y, h1v, fmaf(v1.z, h2, fmaf(v1.w, h3, a1))));
      }
      sm.red[ks][0][b] = a0;
      sm.red[ks][1][b] = a1;
      __syncthreads();
      if (tid < 64) {
        int rr = tid >> 5, bb = tid & 31;
        float s = 0.0f;
#pragma unroll
        for (int kk = 0; kk < 8; kk++) s += sm.red[kk][rr][bb];
        s += bf1[r0 + rr];
        gstore(&h1g[(size_t)(r0 + rr) * 32 + bb], fmaxf(s, 0.0f));
      }
    }
    gridbar(flags, ++ep, dead);

    // ---------------- P67: FC2 fine + argmax ----------------
    if (w < NB) {
      int b2 = w;
      for (int i = tid; i < HALFN; i += NTHR) sm.h1col[i] = gload(&h1g[(size_t)i * 32 + b2]);
      __syncthreads();
      float accv = bf2[tid];
      const float* wrow2 = wf2 + (size_t)tid * HALFN;
      for (int i = 0; i < HALFN; i += 4) {
        float4 wv = *(const float4*)(wrow2 + i);
        accv = fmaf(wv.x, sm.h1col[i],
               fmaf(wv.y, sm.h1col[i + 1],
               fmaf(wv.z, sm.h1col[i + 2],
               fmaf(wv.w, sm.h1col[i + 3], accv))));
      }
      float v = accv; int vi = tid;
#pragma unroll
      for (int off = 1; off < 64; off <<= 1) {
        float ov = __shfl_xor(v, off);
        int   oi = __shfl_xor(vi, off);
        if (ov > v || (ov == v && oi < vi)) { v = ov; vi = oi; }
      }
      int wave = tid >> 6;
      if ((tid & 63) == 0) { sm.amaxv[wave] = v; sm.amaxi[wave] = vi; }
      __syncthreads();
      if (tid == 0) {
        float bv = sm.amaxv[0]; int bi = sm.amaxi[0];
#pragma unroll
        for (int q = 1; q < 4; q++) {
          float qv = sm.amaxv[q]; int qi = sm.amaxi[q];
          if (qv > bv || (qv == bv && qi < bi)) { bv = qv; bi = qi; }
        }
        sm.bcast = bi;
      }
      __syncthreads();
      int nf = sm.bcast;
      if (tid == 0) {
        out[32768 + (size_t)b2 * TSTEPS + t] = (float)nf;
        gstore(&fsamp[b2], (float)nf);
      }
    }
    gridbar(flags, ++ep, dead);
  }

  // final hidden: [c_hid; f_hid] (896 x 32), newest buffer is buf0 after t=1023
  if (w < NB) {
    for (int j = tid; j < SIZEN; j += NTHR)
      out[65536 + (size_t)j * 32 + w] = gload(&hidbuf0[(size_t)j * 32 + w]);
  }
}

extern "C" void kernel_launch(void* const* d_in, const int* in_sizes, int n_in,
                              void* d_out, int out_size, void* d_ws, size_t ws_size,
                              hipStream_t stream) {
  const float* cond = (const float*)d_in[0];
  const float* wci  = (const float*)d_in[1];
  const float* wfi  = (const float*)d_in[2];
  const float* whh  = (const float*)d_in[3];
  const float* bih  = (const float*)d_in[4];
  const float* bhh  = (const float*)d_in[5];
  const float* wc1  = (const float*)d_in[6];
  const float* bc1  = (const float*)d_in[7];
  const float* wc2  = (const float*)d_in[8];
  const float* bc2  = (const float*)d_in[9];
  const float* wf1  = (const float*)d_in[10];
  const float* bf1  = (const float*)d_in[11];
  const float* wf2  = (const float*)d_in[12];
  const float* bf2  = (const float*)d_in[13];
  float* out = (float*)d_out;
  float* ws  = (float*)d_ws;

  hipLaunchKernelGGL(wavernn_init, dim3(64), dim3(NTHR), 0, stream, ws);
  hipLaunchKernelGGL(wavernn_persist, dim3(NWG), dim3(NTHR), 0, stream,
                     cond, wci, wfi, whh, bih, bhh,
                     wc1, bc1, wc2, bc2, wf1, bf1, wf2, bf2, out, ws);
}